// Round 1
// 374.561 us; speedup vs baseline: 1.0060x; 1.0060x over previous
//
#include <hip/hip_runtime.h>

// LIF dual forward: x [T,B,N,C] f32, decay scalar.
// out = concat(spikes [T,B,N,C] f32, vpool [T,B,C] f32) flat.
//
// R6: scheduling rebuild. Previous grid was 896 blocks x 448 thr with
// __launch_bounds__(448,2) -- that 2nd arg is waves/EU, so only ONE 7-wave
// block was guaranteed resident per CU, and 896 blocks over <=512 slots
// leaves a 12.5%+ ragged tail. New shape: 512 blocks x 256 thr (64x4),
// __launch_bounds__(256,2) => 2 blocks/CU guaranteed co-resident (4-wave
// blocks, VGPR cap 256 so no spill pressure), grid == exactly 2 blocks/CU
// => zero tail. N=196 rows split 8 groups/(b,cc): 4x25 + 4x24 rows,
// worst-case imbalance ~2%. Each thread walks ~6-7 rows, t-loop unrolled
// in regs, vpsum[16] accumulated across all its rows.
// R5 (kept): x loads NON-TEMPORAL -- harness poisons d_out into L3 right
// before launch; nt x-loads don't allocate in L3 so our plain spike stores
// absorb the poisoned lines in-cache instead of forcing an HBM drain.
constexpr int T   = 16;
constexpr int B   = 32;
constexpr int N   = 196;
constexpr int C   = 512;
constexpr int C4  = C / 4;     // 128 float4 columns
constexpr int TX  = 64;        // c4 lanes per block (one wave per ty row)
constexpr int TY  = 4;         // rows in flight per block
constexpr int NGRP = 8;        // row-groups per (b, c-half): 4x25 + 4x24
constexpr int PCHUNK_F4 = T * B * C4;   // f32x4 per partial chunk = 65536

typedef float f32x4 __attribute__((ext_vector_type(4)));

__global__ __launch_bounds__(TX * TY, 2) void lif_stage1(
    const f32x4* __restrict__ x,
    const float* __restrict__ decay,
    f32x4* __restrict__ spikes,
    f32x4* __restrict__ partial) {          // [NGRP][T][B][C4] f32x4
  __shared__ f32x4 red[TY][4][TX];          // 16 KB

  const int tx = threadIdx.x;               // 0..63
  const int ty = threadIdx.y;               // 0..3
  const int cc = blockIdx.x;                // 0..1  (c-half)
  const int gi = blockIdx.y;                // 0..7  (row group)
  const int b  = blockIdx.z;                // 0..31

  const int c4 = cc * TX + tx;              // 0..127
  const float d = decay[0];

  // 196 = 8*24 + 4: groups 0..3 get 25 rows, 4..7 get 24.
  const int start = gi * 24 + (gi < 4 ? gi : 4);
  const int count = 24 + (gi < 4 ? 1 : 0);

  f32x4 vpsum[T];
#pragma unroll
  for (int t = 0; t < T; ++t) vpsum[t] = (f32x4)(0.f);

  const size_t tstride = (size_t)B * N * C4;   // f32x4 units

  // Each wave (== one ty) owns rows start+ty, start+ty+4, ... (wave-uniform
  // trip counts; only wave ty=0 takes the extra row when count==25).
  for (int n = start + ty; n < start + count; n += TY) {
    size_t idx = ((size_t)b * N + n) * C4 + c4;
    f32x4 v = (f32x4)(0.f);

#pragma unroll
    for (int t = 0; t < T; ++t) {
      // x is read exactly once per launch: non-temporal (don't pollute L3,
      // keep poisoned d_out lines resident for our stores to absorb).
      f32x4 xt = __builtin_nontemporal_load(&x[idx]);

      v.x = d * v.x + xt.x;
      v.y = d * v.y + xt.y;
      v.z = d * v.z + xt.z;
      v.w = d * v.w + xt.w;

      vpsum[t].x += v.x;
      vpsum[t].y += v.y;
      vpsum[t].z += v.z;
      vpsum[t].w += v.w;

      f32x4 s;
      s.x = (v.x >= 1.0f) ? 1.0f : 0.0f;  v.x = (v.x >= 1.0f) ? 0.0f : v.x;
      s.y = (v.y >= 1.0f) ? 1.0f : 0.0f;  v.y = (v.y >= 1.0f) ? 0.0f : v.y;
      s.z = (v.z >= 1.0f) ? 1.0f : 0.0f;  v.z = (v.z >= 1.0f) ? 0.0f : v.z;
      s.w = (v.w >= 1.0f) ? 1.0f : 0.0f;  v.w = (v.w >= 1.0f) ? 0.0f : v.w;

      spikes[idx] = s;   // plain store: overwrite poisoned line in L2/L3
      idx += tstride;
    }
  }

  // Reduce vpsum over the 4 ty waves via LDS, 4 t per round; plain stores.
  const int flat = ty * TX + tx;            // 0..255
#pragma unroll 1
  for (int tc = 0; tc < T; tc += 4) {
#pragma unroll
    for (int j = 0; j < 4; ++j) red[ty][j][tx] = vpsum[tc + j];
    __syncthreads();
    {
      const int j   = flat >> 6;            // 0..3
      const int col = flat & 63;            // 0..63
      f32x4 a = red[0][j][col];
#pragma unroll
      for (int k = 1; k < TY; ++k) {
        f32x4 r2 = red[k][j][col];
        a.x += r2.x; a.y += r2.y; a.z += r2.z; a.w += r2.w;
      }
      const int t = tc + j;
      const size_t pidx = (size_t)gi * PCHUNK_F4 +
                          ((size_t)t * B + b) * C4 + (cc * TX + col);
      partial[pidx] = a;
    }
    __syncthreads();
  }
}

__global__ __launch_bounds__(256) void lif_stage2(
    const f32x4* __restrict__ partial,      // [NGRP][T*B*C4] f32x4
    f32x4* __restrict__ vpool) {            // [T*B*C4] f32x4
  const int gid = blockIdx.x * 256 + threadIdx.x;   // 0..65535
  const float inv_n = 1.0f / (float)N;
  f32x4 a = partial[gid];
#pragma unroll
  for (int k = 1; k < NGRP; ++k) {
    f32x4 r = partial[(size_t)k * PCHUNK_F4 + gid];
    a.x += r.x; a.y += r.y; a.z += r.z; a.w += r.w;
  }
  a.x *= inv_n; a.y *= inv_n; a.z *= inv_n; a.w *= inv_n;
  vpool[gid] = a;
}

extern "C" void kernel_launch(void* const* d_in, const int* in_sizes, int n_in,
                              void* d_out, int out_size, void* d_ws, size_t ws_size,
                              hipStream_t stream) {
  const f32x4* x      = (const f32x4*)d_in[0];
  const float* decay  = (const float*)d_in[1];

  float* out = (float*)d_out;
  const size_t spike_elems = (size_t)T * B * N * C;   // 51,380,224

  f32x4* spikes  = (f32x4*)out;
  f32x4* vpool   = (f32x4*)(out + spike_elems);
  f32x4* partial = (f32x4*)d_ws;   // needs NGRP*T*B*C floats = 8.4 MB

  dim3 block1(TX, TY);                     // 64 x 4 = 256 threads (4 waves)
  dim3 grid1(2, NGRP, B);                  // 2 x 8 x 32 = 512 blocks = 2/CU exact
  lif_stage1<<<grid1, block1, 0, stream>>>(x, decay, spikes, partial);

  lif_stage2<<<dim3(PCHUNK_F4 / 256), dim3(256), 0, stream>>>(partial, vpool);
}

// Round 2
// 358.917 us; speedup vs baseline: 1.0498x; 1.0436x over previous
//
#include <hip/hip_runtime.h>

// LIF dual forward: x [T,B,N,C] f32, decay scalar.
// out = concat(spikes [T,B,N,C] f32, vpool [T,B,C] f32) flat.
//
// R7: SCRATCH FIX. R6's counters showed VGPR_Count=44 for stage1, but
// vpsum[16] x f32x4 alone is 64 registers -> the accumulator array was
// demoted to scratch. Cause: the reduction loop was `#pragma unroll 1`,
// making vpsum[tc+j] a RUNTIME index (rule #20: runtime-indexed arrays
// go to local memory). Every hot-loop accumulate was a scratch RMW,
// which is why stage1 ran at 3.0 TB/s (132 us) vs the ~63 us roofline
// for its 396 MB of HBM traffic. Fix: fully unroll the tc loop so every
// vpsum index is compile-time constant; vpsum stays in VGPRs.
// R6 (kept): 512 blocks x 256 thr (64x4), __launch_bounds__(256,2) ->
// exactly 2 blocks/CU, zero tail; N=196 split 4x25+4x24 row groups.
// R5 (kept): x loads NON-TEMPORAL -- harness poisons d_out into L3 right
// before launch; nt x-loads don't allocate in L3 so our plain spike
// stores absorb the poisoned lines in-cache instead of draining to HBM.
constexpr int T   = 16;
constexpr int B   = 32;
constexpr int N   = 196;
constexpr int C   = 512;
constexpr int C4  = C / 4;     // 128 float4 columns
constexpr int TX  = 64;        // c4 lanes per block (one wave per ty row)
constexpr int TY  = 4;         // rows in flight per block
constexpr int NGRP = 8;        // row-groups per (b, c-half): 4x25 + 4x24
constexpr int PCHUNK_F4 = T * B * C4;   // f32x4 per partial chunk = 65536

typedef float f32x4 __attribute__((ext_vector_type(4)));

__global__ __launch_bounds__(TX * TY, 2) void lif_stage1(
    const f32x4* __restrict__ x,
    const float* __restrict__ decay,
    f32x4* __restrict__ spikes,
    f32x4* __restrict__ partial) {          // [NGRP][T][B][C4] f32x4
  __shared__ f32x4 red[TY][4][TX];          // 16 KB

  const int tx = threadIdx.x;               // 0..63
  const int ty = threadIdx.y;               // 0..3
  const int cc = blockIdx.x;                // 0..1  (c-half)
  const int gi = blockIdx.y;                // 0..7  (row group)
  const int b  = blockIdx.z;                // 0..31

  const int c4 = cc * TX + tx;              // 0..127
  const float d = decay[0];

  // 196 = 8*24 + 4: groups 0..3 get 25 rows, 4..7 get 24.
  const int start = gi * 24 + (gi < 4 ? gi : 4);
  const int count = 24 + (gi < 4 ? 1 : 0);

  f32x4 vpsum[T];
#pragma unroll
  for (int t = 0; t < T; ++t) vpsum[t] = (f32x4)(0.f);

  const size_t tstride = (size_t)B * N * C4;   // f32x4 units

  // Each wave (== one ty) owns rows start+ty, start+ty+4, ... (wave-uniform
  // trip counts; only wave ty=0 takes the extra row when count==25).
  for (int n = start + ty; n < start + count; n += TY) {
    size_t idx = ((size_t)b * N + n) * C4 + c4;
    f32x4 v = (f32x4)(0.f);

#pragma unroll
    for (int t = 0; t < T; ++t) {
      // x is read exactly once per launch: non-temporal (don't pollute L3,
      // keep poisoned d_out lines resident for our stores to absorb).
      f32x4 xt = __builtin_nontemporal_load(&x[idx]);

      v.x = d * v.x + xt.x;
      v.y = d * v.y + xt.y;
      v.z = d * v.z + xt.z;
      v.w = d * v.w + xt.w;

      vpsum[t].x += v.x;
      vpsum[t].y += v.y;
      vpsum[t].z += v.z;
      vpsum[t].w += v.w;

      f32x4 s;
      s.x = (v.x >= 1.0f) ? 1.0f : 0.0f;  v.x = (v.x >= 1.0f) ? 0.0f : v.x;
      s.y = (v.y >= 1.0f) ? 1.0f : 0.0f;  v.y = (v.y >= 1.0f) ? 0.0f : v.y;
      s.z = (v.z >= 1.0f) ? 1.0f : 0.0f;  v.z = (v.z >= 1.0f) ? 0.0f : v.z;
      s.w = (v.w >= 1.0f) ? 1.0f : 0.0f;  v.w = (v.w >= 1.0f) ? 0.0f : v.w;

      spikes[idx] = s;   // plain store: overwrite poisoned line in L2/L3
      idx += tstride;
    }
  }

  // Reduce vpsum over the 4 ty waves via LDS, 4 t per round.
  // FULLY UNROLLED (tc is compile-time) so vpsum indices are static and
  // the array stays in VGPRs -- see R7 note above.
  const int flat = ty * TX + tx;            // 0..255
  const int jj   = flat >> 6;               // 0..3
  const int col  = flat & 63;               // 0..63
#pragma unroll
  for (int tc = 0; tc < T; tc += 4) {
#pragma unroll
    for (int j = 0; j < 4; ++j) red[ty][j][tx] = vpsum[tc + j];
    __syncthreads();
    {
      f32x4 a = red[0][jj][col];
#pragma unroll
      for (int k = 1; k < TY; ++k) {
        f32x4 r2 = red[k][jj][col];
        a.x += r2.x; a.y += r2.y; a.z += r2.z; a.w += r2.w;
      }
      const int t = tc + jj;
      const size_t pidx = (size_t)gi * PCHUNK_F4 +
                          ((size_t)t * B + b) * C4 + (cc * TX + col);
      partial[pidx] = a;
    }
    __syncthreads();
  }
}

__global__ __launch_bounds__(256) void lif_stage2(
    const f32x4* __restrict__ partial,      // [NGRP][T*B*C4] f32x4
    f32x4* __restrict__ vpool) {            // [T*B*C4] f32x4
  const int gid = blockIdx.x * 256 + threadIdx.x;   // 0..65535
  const float inv_n = 1.0f / (float)N;
  f32x4 a = partial[gid];
#pragma unroll
  for (int k = 1; k < NGRP; ++k) {
    f32x4 r = partial[(size_t)k * PCHUNK_F4 + gid];
    a.x += r.x; a.y += r.y; a.z += r.z; a.w += r.w;
  }
  a.x *= inv_n; a.y *= inv_n; a.z *= inv_n; a.w *= inv_n;
  vpool[gid] = a;
}

extern "C" void kernel_launch(void* const* d_in, const int* in_sizes, int n_in,
                              void* d_out, int out_size, void* d_ws, size_t ws_size,
                              hipStream_t stream) {
  const f32x4* x      = (const f32x4*)d_in[0];
  const float* decay  = (const float*)d_in[1];

  float* out = (float*)d_out;
  const size_t spike_elems = (size_t)T * B * N * C;   // 51,380,224

  f32x4* spikes  = (f32x4*)out;
  f32x4* vpool   = (f32x4*)(out + spike_elems);
  f32x4* partial = (f32x4*)d_ws;   // needs NGRP*T*B*C floats = 8.4 MB

  dim3 block1(TX, TY);                     // 64 x 4 = 256 threads (4 waves)
  dim3 grid1(2, NGRP, B);                  // 2 x 8 x 32 = 512 blocks = 2/CU exact
  lif_stage1<<<grid1, block1, 0, stream>>>(x, decay, spikes, partial);

  lif_stage2<<<dim3(PCHUNK_F4 / 256), dim3(256), 0, stream>>>(partial, vpool);
}

// Round 3
// 353.140 us; speedup vs baseline: 1.0670x; 1.0164x over previous
//
#include <hip/hip_runtime.h>

// LIF dual forward: x [T,B,N,C] f32, decay scalar.
// out = concat(spikes [T,B,N,C] f32, vpool [T,B,C] f32) flat.
//
// R8: OCCUPANCY x2. R7 fixed the vpsum scratch demotion (stage1 ~132 ->
// ~98 us) but stage1 still runs ~1.5x off its ~66 us roofline (420 MB).
// Remaining gap = latency hiding: only 2 blocks/CU x 4 waves = 2 waves/
// SIMD resident. This round: __launch_bounds__(256,4) (VGPR cap 128;
// static need ~90 so no spill) + NGRP 8->16 => grid 1024 = exactly
// 4 blocks/CU, still zero tail. 196 rows = 4 groups x13 + 12 groups x12.
// R7 (kept): reduction tc-loop fully unrolled -> vpsum statically
// indexed, stays in VGPRs (rule #20).
// R5 (kept): x loads NON-TEMPORAL -- harness poisons d_out into L3 right
// before launch; nt x-loads don't allocate in L3 so our plain spike
// stores absorb the poisoned lines in-cache instead of draining to HBM.
constexpr int T   = 16;
constexpr int B   = 32;
constexpr int N   = 196;
constexpr int C   = 512;
constexpr int C4  = C / 4;     // 128 float4 columns
constexpr int TX  = 64;        // c4 lanes per block (one wave per ty row)
constexpr int TY  = 4;         // rows in flight per block
constexpr int NGRP = 16;       // row-groups per (b, c-half): 4x13 + 12x12
constexpr int PCHUNK_F4 = T * B * C4;   // f32x4 per partial chunk = 65536

typedef float f32x4 __attribute__((ext_vector_type(4)));

__global__ __launch_bounds__(TX * TY, 4) void lif_stage1(
    const f32x4* __restrict__ x,
    const float* __restrict__ decay,
    f32x4* __restrict__ spikes,
    f32x4* __restrict__ partial) {          // [NGRP][T][B][C4] f32x4
  __shared__ f32x4 red[TY][4][TX];          // 16 KB (4 blocks/CU -> 64 KB)

  const int tx = threadIdx.x;               // 0..63
  const int ty = threadIdx.y;               // 0..3
  const int cc = blockIdx.x;                // 0..1  (c-half)
  const int gi = blockIdx.y;                // 0..15 (row group)
  const int b  = blockIdx.z;                // 0..31

  const int c4 = cc * TX + tx;              // 0..127
  const float d = decay[0];

  // 196 = 16*12 + 4: groups 0..3 get 13 rows, 4..15 get 12.
  const int start = gi * 12 + (gi < 4 ? gi : 4);
  const int count = 12 + (gi < 4 ? 1 : 0);

  f32x4 vpsum[T];
#pragma unroll
  for (int t = 0; t < T; ++t) vpsum[t] = (f32x4)(0.f);

  const size_t tstride = (size_t)B * N * C4;   // f32x4 units

  // Each wave (== one ty) owns rows start+ty, start+ty+4, ... (wave-uniform
  // trip counts; only wave ty=0 takes the extra row when count==13).
  for (int n = start + ty; n < start + count; n += TY) {
    size_t idx = ((size_t)b * N + n) * C4 + c4;
    f32x4 v = (f32x4)(0.f);

#pragma unroll
    for (int t = 0; t < T; ++t) {
      // x is read exactly once per launch: non-temporal (don't pollute L3,
      // keep poisoned d_out lines resident for our stores to absorb).
      f32x4 xt = __builtin_nontemporal_load(&x[idx]);

      v.x = d * v.x + xt.x;
      v.y = d * v.y + xt.y;
      v.z = d * v.z + xt.z;
      v.w = d * v.w + xt.w;

      vpsum[t].x += v.x;
      vpsum[t].y += v.y;
      vpsum[t].z += v.z;
      vpsum[t].w += v.w;

      f32x4 s;
      s.x = (v.x >= 1.0f) ? 1.0f : 0.0f;  v.x = (v.x >= 1.0f) ? 0.0f : v.x;
      s.y = (v.y >= 1.0f) ? 1.0f : 0.0f;  v.y = (v.y >= 1.0f) ? 0.0f : v.y;
      s.z = (v.z >= 1.0f) ? 1.0f : 0.0f;  v.z = (v.z >= 1.0f) ? 0.0f : v.z;
      s.w = (v.w >= 1.0f) ? 1.0f : 0.0f;  v.w = (v.w >= 1.0f) ? 0.0f : v.w;

      spikes[idx] = s;   // plain store: overwrite poisoned line in L2/L3
      idx += tstride;
    }
  }

  // Reduce vpsum over the 4 ty waves via LDS, 4 t per round.
  // FULLY UNROLLED (tc is compile-time) so vpsum indices are static and
  // the array stays in VGPRs (R7).
  const int flat = ty * TX + tx;            // 0..255
  const int jj   = flat >> 6;               // 0..3
  const int col  = flat & 63;               // 0..63
#pragma unroll
  for (int tc = 0; tc < T; tc += 4) {
#pragma unroll
    for (int j = 0; j < 4; ++j) red[ty][j][tx] = vpsum[tc + j];
    __syncthreads();
    {
      f32x4 a = red[0][jj][col];
#pragma unroll
      for (int k = 1; k < TY; ++k) {
        f32x4 r2 = red[k][jj][col];
        a.x += r2.x; a.y += r2.y; a.z += r2.z; a.w += r2.w;
      }
      const int t = tc + jj;
      const size_t pidx = (size_t)gi * PCHUNK_F4 +
                          ((size_t)t * B + b) * C4 + (cc * TX + col);
      partial[pidx] = a;
    }
    __syncthreads();
  }
}

__global__ __launch_bounds__(256) void lif_stage2(
    const f32x4* __restrict__ partial,      // [NGRP][T*B*C4] f32x4
    f32x4* __restrict__ vpool) {            // [T*B*C4] f32x4
  const int gid = blockIdx.x * 256 + threadIdx.x;   // 0..65535
  const float inv_n = 1.0f / (float)N;
  f32x4 a = partial[gid];
#pragma unroll
  for (int k = 1; k < NGRP; ++k) {
    f32x4 r = partial[(size_t)k * PCHUNK_F4 + gid];
    a.x += r.x; a.y += r.y; a.z += r.z; a.w += r.w;
  }
  a.x *= inv_n; a.y *= inv_n; a.z *= inv_n; a.w *= inv_n;
  vpool[gid] = a;
}

extern "C" void kernel_launch(void* const* d_in, const int* in_sizes, int n_in,
                              void* d_out, int out_size, void* d_ws, size_t ws_size,
                              hipStream_t stream) {
  const f32x4* x      = (const f32x4*)d_in[0];
  const float* decay  = (const float*)d_in[1];

  float* out = (float*)d_out;
  const size_t spike_elems = (size_t)T * B * N * C;   // 51,380,224

  f32x4* spikes  = (f32x4*)out;
  f32x4* vpool   = (f32x4*)(out + spike_elems);
  f32x4* partial = (f32x4*)d_ws;   // needs NGRP*T*B*C floats = 16.8 MB

  dim3 block1(TX, TY);                     // 64 x 4 = 256 threads (4 waves)
  dim3 grid1(2, NGRP, B);                  // 2 x 16 x 32 = 1024 blocks = 4/CU exact
  lif_stage1<<<grid1, block1, 0, stream>>>(x, decay, spikes, partial);

  lif_stage2<<<dim3(PCHUNK_F4 / 256), dim3(256), 0, stream>>>(partial, vpool);
}

// Round 4
// 352.137 us; speedup vs baseline: 1.0701x; 1.0028x over previous
//
#include <hip/hip_runtime.h>

// LIF dual forward: x [T,B,N,C] f32, decay scalar.
// out = concat(spikes [T,B,N,C] f32, vpool [T,B,C] f32) flat.
//
// R9: ILP + ADDRESS DIET. Stage1 sits at ~95 us vs ~68 us BW floor; VALU
// aggregate (~58 us) is close enough to the memory floor that imperfect
// overlap is visible. Two cuts: (1) each wave now walks TWO rows (n, n+TY)
// interleaved in one t-loop -> 2 independent recurrence/load chains per
// wave (double vmcnt depth, half loop trips), rows' v pre-summed before
// the vpsum accumulate; (2) 32-bit byte offsets (x, spikes each 205.5 MB
// < 4 GB) -> SGPR-base + u32 voffset addressing, one v_add_u32 per t
// shared by load+store instead of 64-bit carry pairs.
// R8 (kept): 1024 blocks x 256 thr, __launch_bounds__(256,4) = exactly
// 4 blocks/CU, zero tail; 196 rows = 4 groups x13 + 12 x12.
// R7 (kept): reduction tc-loop fully unrolled -> vpsum statically
// indexed, stays in VGPRs (rule #20).
// R5 (kept): x loads NON-TEMPORAL -- harness poisons d_out into L3; nt
// x-loads don't allocate in L3 so plain spike stores absorb the poisoned
// lines in-cache instead of draining them to HBM.
constexpr int T   = 16;
constexpr int B   = 32;
constexpr int N   = 196;
constexpr int C   = 512;
constexpr int C4  = C / 4;     // 128 float4 columns
constexpr int TX  = 64;        // c4 lanes per block (one wave per ty row)
constexpr int TY  = 4;         // rows in flight per block
constexpr int NGRP = 16;       // row-groups per (b, c-half): 4x13 + 12x12
constexpr int PCHUNK_F4 = T * B * C4;   // f32x4 per partial chunk = 65536

typedef float f32x4 __attribute__((ext_vector_type(4)));

__device__ __forceinline__ void lif_step(float d, f32x4 xt, f32x4& v, f32x4& s) {
  v.x = d * v.x + xt.x;
  v.y = d * v.y + xt.y;
  v.z = d * v.z + xt.z;
  v.w = d * v.w + xt.w;
  s.x = (v.x >= 1.0f) ? 1.0f : 0.0f;
  s.y = (v.y >= 1.0f) ? 1.0f : 0.0f;
  s.z = (v.z >= 1.0f) ? 1.0f : 0.0f;
  s.w = (v.w >= 1.0f) ? 1.0f : 0.0f;
}

__device__ __forceinline__ void lif_reset(f32x4& v) {
  v.x = (v.x >= 1.0f) ? 0.0f : v.x;
  v.y = (v.y >= 1.0f) ? 0.0f : v.y;
  v.z = (v.z >= 1.0f) ? 0.0f : v.z;
  v.w = (v.w >= 1.0f) ? 0.0f : v.w;
}

__global__ __launch_bounds__(TX * TY, 4) void lif_stage1(
    const f32x4* __restrict__ x,
    const float* __restrict__ decay,
    f32x4* __restrict__ spikes,
    f32x4* __restrict__ partial) {          // [NGRP][T][B][C4] f32x4
  __shared__ f32x4 red[TY][4][TX];          // 16 KB (4 blocks/CU -> 64 KB)

  const int tx = threadIdx.x;               // 0..63
  const int ty = threadIdx.y;               // 0..3
  const int cc = blockIdx.x;                // 0..1  (c-half)
  const int gi = blockIdx.y;                // 0..15 (row group)
  const int b  = blockIdx.z;                // 0..31

  const int c4 = cc * TX + tx;              // 0..127
  const float d = decay[0];

  // 196 = 16*12 + 4: groups 0..3 get 13 rows, 4..15 get 12.
  const int start = gi * 12 + (gi < 4 ? gi : 4);
  const int count = 12 + (gi < 4 ? 1 : 0);

  f32x4 vpsum[T];
#pragma unroll
  for (int t = 0; t < T; ++t) vpsum[t] = (f32x4)(0.f);

  // 32-bit byte offsets: x / spikes are 205.5 MB each, fits u32.
  const char* xb = (const char*)x;
  char*       sb = (char*)spikes;
  const unsigned tstride_b = (unsigned)(B * N * C4) * 16u;  // bytes per t
  const unsigned rstride_b = (unsigned)(TY * C4) * 16u;     // bytes per +TY rows

  int n = start + ty;
  const int nEnd = start + count;

  // Pairs of rows (n, n+TY): two independent recurrence chains per wave.
  for (; n + TY < nEnd; n += 2 * TY) {
    unsigned off0 = (((unsigned)b * N + n) * C4 + c4) * 16u;
    unsigned off1 = off0 + rstride_b;
    f32x4 va = (f32x4)(0.f), vb = (f32x4)(0.f);

#pragma unroll
    for (int t = 0; t < T; ++t) {
      f32x4 xa = __builtin_nontemporal_load((const f32x4*)(xb + off0));
      f32x4 xc = __builtin_nontemporal_load((const f32x4*)(xb + off1));

      f32x4 sa, sc;
      lif_step(d, xa, va, sa);
      lif_step(d, xc, vb, sc);

      vpsum[t].x += va.x + vb.x;
      vpsum[t].y += va.y + vb.y;
      vpsum[t].z += va.z + vb.z;
      vpsum[t].w += va.w + vb.w;

      *(f32x4*)(sb + off0) = sa;   // plain store: absorb poisoned L3 line
      *(f32x4*)(sb + off1) = sc;
      lif_reset(va);
      lif_reset(vb);

      off0 += tstride_b;
      off1 += tstride_b;
    }
  }

  // Leftover single row (waves with an odd row count).
  if (n < nEnd) {
    unsigned off0 = (((unsigned)b * N + n) * C4 + c4) * 16u;
    f32x4 va = (f32x4)(0.f);
#pragma unroll
    for (int t = 0; t < T; ++t) {
      f32x4 xa = __builtin_nontemporal_load((const f32x4*)(xb + off0));
      f32x4 sa;
      lif_step(d, xa, va, sa);
      vpsum[t].x += va.x;
      vpsum[t].y += va.y;
      vpsum[t].z += va.z;
      vpsum[t].w += va.w;
      *(f32x4*)(sb + off0) = sa;
      lif_reset(va);
      off0 += tstride_b;
    }
  }

  // Reduce vpsum over the 4 ty waves via LDS, 4 t per round.
  // FULLY UNROLLED (tc is compile-time) so vpsum indices are static and
  // the array stays in VGPRs (R7).
  const int flat = ty * TX + tx;            // 0..255
  const int jj   = flat >> 6;               // 0..3
  const int col  = flat & 63;               // 0..63
#pragma unroll
  for (int tc = 0; tc < T; tc += 4) {
#pragma unroll
    for (int j = 0; j < 4; ++j) red[ty][j][tx] = vpsum[tc + j];
    __syncthreads();
    {
      f32x4 a = red[0][jj][col];
#pragma unroll
      for (int k = 1; k < TY; ++k) {
        f32x4 r2 = red[k][jj][col];
        a.x += r2.x; a.y += r2.y; a.z += r2.z; a.w += r2.w;
      }
      const int t = tc + jj;
      const size_t pidx = (size_t)gi * PCHUNK_F4 +
                          ((size_t)t * B + b) * C4 + (cc * TX + col);
      partial[pidx] = a;
    }
    __syncthreads();
  }
}

__global__ __launch_bounds__(256) void lif_stage2(
    const f32x4* __restrict__ partial,      // [NGRP][T*B*C4] f32x4
    f32x4* __restrict__ vpool) {            // [T*B*C4] f32x4
  const int gid = blockIdx.x * 256 + threadIdx.x;   // 0..65535
  const float inv_n = 1.0f / (float)N;
  f32x4 a = partial[gid];
#pragma unroll
  for (int k = 1; k < NGRP; ++k) {
    f32x4 r = partial[(size_t)k * PCHUNK_F4 + gid];
    a.x += r.x; a.y += r.y; a.z += r.z; a.w += r.w;
  }
  a.x *= inv_n; a.y *= inv_n; a.z *= inv_n; a.w *= inv_n;
  vpool[gid] = a;
}

extern "C" void kernel_launch(void* const* d_in, const int* in_sizes, int n_in,
                              void* d_out, int out_size, void* d_ws, size_t ws_size,
                              hipStream_t stream) {
  const f32x4* x      = (const f32x4*)d_in[0];
  const float* decay  = (const float*)d_in[1];

  float* out = (float*)d_out;
  const size_t spike_elems = (size_t)T * B * N * C;   // 51,380,224

  f32x4* spikes  = (f32x4*)out;
  f32x4* vpool   = (f32x4*)(out + spike_elems);
  f32x4* partial = (f32x4*)d_ws;   // needs NGRP*T*B*C floats = 16.8 MB

  dim3 block1(TX, TY);                     // 64 x 4 = 256 threads (4 waves)
  dim3 grid1(2, NGRP, B);                  // 2 x 16 x 32 = 1024 blocks = 4/CU exact
  lif_stage1<<<grid1, block1, 0, stream>>>(x, decay, spikes, partial);

  lif_stage2<<<dim3(PCHUNK_F4 / 256), dim3(256), 0, stream>>>(partial, vpool);
}

// Round 5
// 342.941 us; speedup vs baseline: 1.0988x; 1.0268x over previous
//
#include <hip/hip_runtime.h>

// LIF dual forward: x [T,B,N,C] f32, decay scalar.
// out = concat(spikes [T,B,N,C] f32, vpool [T,B,C] f32) flat.
//
// R10: NT SPIKE STORES. R9 was neutral and corrected arithmetic shows
// VALU is ~4 us total -- stage1 is pure memory. Remaining theory: our
// plain spike stores (205.5 MB) allocate dirty in L2/L3, (a) evicting
// the x lines that would otherwise survive between bench iterations
// (R6 counters: FETCH 115 MB < 205.5 MB of x => x partially L3-resident
// across iterations), and (b) leaving 200+ MB of dirty lines that the
// NEXT iteration's poison fill must drain against (fill dur drifts
// 125->133 us round-to-round with constant WRITE_SIZE -- coupled to our
// residue). Spikes are never re-read: store them NON-TEMPORAL so they
// stream to HBM without L3 allocation. partial stays a PLAIN store
// (stage2 re-reads it; want L2/L3 hits). Single-variable change vs R9.
// R9 (kept): two-row pairing, 32-bit byte offsets.
// R8 (kept): 1024 blocks x 256 thr, __launch_bounds__(256,4) = exactly
// 4 blocks/CU, zero tail; 196 rows = 4 groups x13 + 12 x12.
// R7 (kept): reduction tc-loop fully unrolled -> vpsum statically
// indexed, stays in VGPRs (rule #20).
// R5 (kept): x loads NON-TEMPORAL.
constexpr int T   = 16;
constexpr int B   = 32;
constexpr int N   = 196;
constexpr int C   = 512;
constexpr int C4  = C / 4;     // 128 float4 columns
constexpr int TX  = 64;        // c4 lanes per block (one wave per ty row)
constexpr int TY  = 4;         // rows in flight per block
constexpr int NGRP = 16;       // row-groups per (b, c-half): 4x13 + 12x12
constexpr int PCHUNK_F4 = T * B * C4;   // f32x4 per partial chunk = 65536

typedef float f32x4 __attribute__((ext_vector_type(4)));

__device__ __forceinline__ void lif_step(float d, f32x4 xt, f32x4& v, f32x4& s) {
  v.x = d * v.x + xt.x;
  v.y = d * v.y + xt.y;
  v.z = d * v.z + xt.z;
  v.w = d * v.w + xt.w;
  s.x = (v.x >= 1.0f) ? 1.0f : 0.0f;
  s.y = (v.y >= 1.0f) ? 1.0f : 0.0f;
  s.z = (v.z >= 1.0f) ? 1.0f : 0.0f;
  s.w = (v.w >= 1.0f) ? 1.0f : 0.0f;
}

__device__ __forceinline__ void lif_reset(f32x4& v) {
  v.x = (v.x >= 1.0f) ? 0.0f : v.x;
  v.y = (v.y >= 1.0f) ? 0.0f : v.y;
  v.z = (v.z >= 1.0f) ? 0.0f : v.z;
  v.w = (v.w >= 1.0f) ? 0.0f : v.w;
}

__global__ __launch_bounds__(TX * TY, 4) void lif_stage1(
    const f32x4* __restrict__ x,
    const float* __restrict__ decay,
    f32x4* __restrict__ spikes,
    f32x4* __restrict__ partial) {          // [NGRP][T][B][C4] f32x4
  __shared__ f32x4 red[TY][4][TX];          // 16 KB (4 blocks/CU -> 64 KB)

  const int tx = threadIdx.x;               // 0..63
  const int ty = threadIdx.y;               // 0..3
  const int cc = blockIdx.x;                // 0..1  (c-half)
  const int gi = blockIdx.y;                // 0..15 (row group)
  const int b  = blockIdx.z;                // 0..31

  const int c4 = cc * TX + tx;              // 0..127
  const float d = decay[0];

  // 196 = 16*12 + 4: groups 0..3 get 13 rows, 4..15 get 12.
  const int start = gi * 12 + (gi < 4 ? gi : 4);
  const int count = 12 + (gi < 4 ? 1 : 0);

  f32x4 vpsum[T];
#pragma unroll
  for (int t = 0; t < T; ++t) vpsum[t] = (f32x4)(0.f);

  // 32-bit byte offsets: x / spikes are 205.5 MB each, fits u32.
  const char* xb = (const char*)x;
  char*       sb = (char*)spikes;
  const unsigned tstride_b = (unsigned)(B * N * C4) * 16u;  // bytes per t
  const unsigned rstride_b = (unsigned)(TY * C4) * 16u;     // bytes per +TY rows

  int n = start + ty;
  const int nEnd = start + count;

  // Pairs of rows (n, n+TY): two independent recurrence chains per wave.
  for (; n + TY < nEnd; n += 2 * TY) {
    unsigned off0 = (((unsigned)b * N + n) * C4 + c4) * 16u;
    unsigned off1 = off0 + rstride_b;
    f32x4 va = (f32x4)(0.f), vb = (f32x4)(0.f);

#pragma unroll
    for (int t = 0; t < T; ++t) {
      f32x4 xa = __builtin_nontemporal_load((const f32x4*)(xb + off0));
      f32x4 xc = __builtin_nontemporal_load((const f32x4*)(xb + off1));

      f32x4 sa, sc;
      lif_step(d, xa, va, sa);
      lif_step(d, xc, vb, sc);

      vpsum[t].x += va.x + vb.x;
      vpsum[t].y += va.y + vb.y;
      vpsum[t].z += va.z + vb.z;
      vpsum[t].w += va.w + vb.w;

      // Spikes are write-once, never re-read: stream past L3 (R10).
      __builtin_nontemporal_store(sa, (f32x4*)(sb + off0));
      __builtin_nontemporal_store(sc, (f32x4*)(sb + off1));
      lif_reset(va);
      lif_reset(vb);

      off0 += tstride_b;
      off1 += tstride_b;
    }
  }

  // Leftover single row (waves with an odd row count).
  if (n < nEnd) {
    unsigned off0 = (((unsigned)b * N + n) * C4 + c4) * 16u;
    f32x4 va = (f32x4)(0.f);
#pragma unroll
    for (int t = 0; t < T; ++t) {
      f32x4 xa = __builtin_nontemporal_load((const f32x4*)(xb + off0));
      f32x4 sa;
      lif_step(d, xa, va, sa);
      vpsum[t].x += va.x;
      vpsum[t].y += va.y;
      vpsum[t].z += va.z;
      vpsum[t].w += va.w;
      __builtin_nontemporal_store(sa, (f32x4*)(sb + off0));
      lif_reset(va);
      off0 += tstride_b;
    }
  }

  // Reduce vpsum over the 4 ty waves via LDS, 4 t per round.
  // FULLY UNROLLED (tc is compile-time) so vpsum indices are static and
  // the array stays in VGPRs (R7).
  const int flat = ty * TX + tx;            // 0..255
  const int jj   = flat >> 6;               // 0..3
  const int col  = flat & 63;               // 0..63
#pragma unroll
  for (int tc = 0; tc < T; tc += 4) {
#pragma unroll
    for (int j = 0; j < 4; ++j) red[ty][j][tx] = vpsum[tc + j];
    __syncthreads();
    {
      f32x4 a = red[0][jj][col];
#pragma unroll
      for (int k = 1; k < TY; ++k) {
        f32x4 r2 = red[k][jj][col];
        a.x += r2.x; a.y += r2.y; a.z += r2.z; a.w += r2.w;
      }
      const int t = tc + jj;
      const size_t pidx = (size_t)gi * PCHUNK_F4 +
                          ((size_t)t * B + b) * C4 + (cc * TX + col);
      partial[pidx] = a;    // PLAIN store: stage2 re-reads this, keep in L2/L3
    }
    __syncthreads();
  }
}

__global__ __launch_bounds__(256) void lif_stage2(
    const f32x4* __restrict__ partial,      // [NGRP][T*B*C4] f32x4
    f32x4* __restrict__ vpool) {            // [T*B*C4] f32x4
  const int gid = blockIdx.x * 256 + threadIdx.x;   // 0..65535
  const float inv_n = 1.0f / (float)N;
  f32x4 a = partial[gid];
#pragma unroll
  for (int k = 1; k < NGRP; ++k) {
    f32x4 r = partial[(size_t)k * PCHUNK_F4 + gid];
    a.x += r.x; a.y += r.y; a.z += r.z; a.w += r.w;
  }
  a.x *= inv_n; a.y *= inv_n; a.z *= inv_n; a.w *= inv_n;
  vpool[gid] = a;
}

extern "C" void kernel_launch(void* const* d_in, const int* in_sizes, int n_in,
                              void* d_out, int out_size, void* d_ws, size_t ws_size,
                              hipStream_t stream) {
  const f32x4* x      = (const f32x4*)d_in[0];
  const float* decay  = (const float*)d_in[1];

  float* out = (float*)d_out;
  const size_t spike_elems = (size_t)T * B * N * C;   // 51,380,224

  f32x4* spikes  = (f32x4*)out;
  f32x4* vpool   = (f32x4*)(out + spike_elems);
  f32x4* partial = (f32x4*)d_ws;   // needs NGRP*T*B*C floats = 16.8 MB

  dim3 block1(TX, TY);                     // 64 x 4 = 256 threads (4 waves)
  dim3 grid1(2, NGRP, B);                  // 2 x 16 x 32 = 1024 blocks = 4/CU exact
  lif_stage1<<<grid1, block1, 0, stream>>>(x, decay, spikes, partial);

  lif_stage2<<<dim3(PCHUNK_F4 / 256), dim3(256), 0, stream>>>(partial, vpool);
}